// Round 10
// baseline (52.180 us; speedup 1.0000x reference)
//
#include <hip/hip_runtime.h>

// ColorReducer — R9 DIAGNOSTIC ROUND (discriminating experiment).
// Real path = R5 verbatim (best, 23.6 us, absmax 0.0). Added: a dummy VALU
// block (~2.8x the real k-loop instruction count) between compute and store,
// kept alive via asm (rule #17), inputs laundered through an opaque zero so
// no CSE with the real pass. Memory traffic unchanged.
//   dur ~24-26  -> VALU hidden -> memory-limited at 4.3 TB/s (cut traffic/accept)
//   dur ~38-45  -> VALU exposed -> cut selection VALU next (+ counters visible)
//
// Exactness (verified R0/R2/R3/R5/R6/R7/R8, absmax 0.0): contract(off);
// pre-doubled pixels (fl(2r*pr)=2*fl(r*pr), fl(2x+2y)=2*fl(x+y) exact);
// k=0 seed == +inf seed with strict <; packed v2f == scalar IEEE RN.
// BANNED: nontemporal stores (R1); readfirstlane SGPR arrays (R4);
// __launch_bounds__ min-waves cap (R4/R6); PPT=2 (R7); half-residency (R3).

typedef float v2f __attribute__((ext_vector_type(2)));

constexpr int HW    = 512 * 512;   // 2^18
constexpr int KCOL  = 16;
constexpr long NPIX = 16L * HW;    // 4,194,304
constexpr int PPT   = 4;

__global__ __launch_bounds__(256) void color_reduce_kernel(
    const float* __restrict__ x,       // (B, 3, H, W)
    const float* __restrict__ pal,     // (16, 3)
    float* __restrict__ out)           // (B, 3, H, W)
{
#pragma clang fp contract(off)
    __shared__ float spal[KCOL * 3];
    if (threadIdx.x < KCOL * 3) spal[threadIdx.x] = pal[threadIdx.x];
    __syncthreads();

    const long t  = (long)blockIdx.x * blockDim.x + threadIdx.x;
    const long n0 = t * PPT;
    const int b   = (int)(n0 >> 18);        // n0 / HW
    const int pix = (int)(n0 & (HW - 1));   // n0 % HW

    const float* base = x + (size_t)b * 3 * HW + pix;
    const float4 rv = *reinterpret_cast<const float4*>(base);
    const float4 gv = *reinterpret_cast<const float4*>(base + HW);
    const float4 bv = *reinterpret_cast<const float4*>(base + 2 * HW);

    const v2f rA = {rv.x, rv.y}, rB = {rv.z, rv.w};
    const v2f gA = {gv.x, gv.y}, gB = {gv.z, gv.w};
    const v2f bA = {bv.x, bv.y}, bB = {bv.z, bv.w};

    const v2f x2A = ((rA * rA) + (gA * gA)) + (bA * bA);
    const v2f x2B = ((rB * rB) + (gB * gB)) + (bB * bB);

    const v2f r2A = rA + rA, g2A = gA + gA, b2A = bA + bA;
    const v2f r2B = rB + rB, g2B = gB + gB, b2B = bB + bB;

    float best0, best1, best2, best3;
    int   k0 = 0, k1 = 0, k2 = 0, k3 = 0;

    {   // k = 0 seeds best (== +inf seed with strict <)
        const float pr = pal[0], pg = pal[1], pb = pal[2];
        const float p2 = ((pr * pr) + (pg * pg)) + (pb * pb);
        const v2f prv = {pr, pr}, pgv = {pg, pg}, pbv = {pb, pb}, p2v = {p2, p2};
        const v2f crA = ((r2A * prv) + (g2A * pgv)) + (b2A * pbv);  // == 2*cross
        const v2f crB = ((r2B * prv) + (g2B * pgv)) + (b2B * pbv);
        const v2f dA  = (x2A - crA) + p2v;
        const v2f dB  = (x2B - crB) + p2v;
        best0 = dA.x; best1 = dA.y; best2 = dB.x; best3 = dB.y;
    }

#pragma unroll
    for (int k = 1; k < KCOL; ++k) {
        const float pr = pal[3 * k + 0];   // uniform -> s_load/SGPR
        const float pg = pal[3 * k + 1];
        const float pb = pal[3 * k + 2];
        const float p2 = ((pr * pr) + (pg * pg)) + (pb * pb);
        const v2f prv = {pr, pr}, pgv = {pg, pg}, pbv = {pb, pb}, p2v = {p2, p2};
        const v2f crA = ((r2A * prv) + (g2A * pgv)) + (b2A * pbv);
        const v2f crB = ((r2B * prv) + (g2B * pgv)) + (b2B * pbv);
        const v2f dA  = (x2A - crA) + p2v;
        const v2f dB  = (x2B - crB) + p2v;
        if (dA.x < best0) { best0 = dA.x; k0 = k; }   // strict <: np.argmin
        if (dA.y < best1) { best1 = dA.y; k1 = k; }
        if (dB.x < best2) { best2 = dB.x; k2 = k; }
        if (dB.y < best3) { best3 = dB.y; k3 = k; }
    }

    // ---------------- DIAGNOSTIC DUMMY VALU BLOCK ----------------
    // ~2.8x the real k-loop instruction count; result consumed by asm only.
    {
        float z = 0.0f;
        asm volatile("" : "+v"(z));            // opaque zero: blocks CSE/fold
        const v2f zv = {z, z};
        const v2f drA = r2A + zv, dgA = g2A + zv, dbA = b2A + zv, dxA = x2A + zv;
        const v2f drB = r2B + zv, dgB = g2B + zv, dbB = b2B + zv, dxB = x2B + zv;
        v2f mnA = dxA, mnB = dxB;
#pragma unroll
        for (int k = 0; k < 64; ++k) {
            const float pr = 0.013f * (float)k + 0.11f;   // pseudo-palette
            const float pg = 0.017f * (float)k + 0.07f;
            const float pb = 0.019f * (float)k + 0.05f;
            const float p2 = ((pr * pr) + (pg * pg)) + (pb * pb);
            const v2f prv = {pr, pr}, pgv = {pg, pg}, pbv = {pb, pb}, p2v = {p2, p2};
            const v2f cA = ((drA * prv) + (dgA * pgv)) + (dbA * pbv);
            const v2f cB = ((drB * prv) + (dgB * pgv)) + (dbB * pbv);
            const v2f dA = (dxA - cA) + p2v;
            const v2f dB = (dxB - cB) + p2v;
            mnA = __builtin_elementwise_min(mnA, dA);
            mnB = __builtin_elementwise_min(mnB, dB);
        }
        float s0 = mnA.x, s1 = mnA.y, s2 = mnB.x, s3 = mnB.y;
        asm volatile("" :: "v"(s0), "v"(s1), "v"(s2), "v"(s3));  // keepalive
    }
    // -------------------------------------------------------------

    const float o0r = spal[3 * k0 + 0], o0g = spal[3 * k0 + 1], o0b = spal[3 * k0 + 2];
    const float o1r = spal[3 * k1 + 0], o1g = spal[3 * k1 + 1], o1b = spal[3 * k1 + 2];
    const float o2r = spal[3 * k2 + 0], o2g = spal[3 * k2 + 1], o2b = spal[3 * k2 + 2];
    const float o3r = spal[3 * k3 + 0], o3g = spal[3 * k3 + 1], o3b = spal[3 * k3 + 2];

    float* ob = out + (size_t)b * 3 * HW + pix;
    *reinterpret_cast<float4*>(ob)          = make_float4(o0r, o1r, o2r, o3r);
    *reinterpret_cast<float4*>(ob + HW)     = make_float4(o0g, o1g, o2g, o3g);
    *reinterpret_cast<float4*>(ob + 2 * HW) = make_float4(o0b, o1b, o2b, o3b);
}

extern "C" void kernel_launch(void* const* d_in, const int* in_sizes, int n_in,
                              void* d_out, int out_size, void* d_ws, size_t ws_size,
                              hipStream_t stream) {
    const float* x   = (const float*)d_in[0];
    const float* pal = (const float*)d_in[1];
    float* out       = (float*)d_out;

    const int threads = 256;
    const long total_threads = NPIX / PPT;              // 1,048,576
    const int blocks = (int)(total_threads / threads);  // 4096
    color_reduce_kernel<<<blocks, threads, 0, stream>>>(x, pal, out);
}

// Round 11
// 25.621 us; speedup vs baseline: 2.0366x; 2.0366x over previous
//
#include <hip/hip_runtime.h>

// ColorReducer: per-pixel argmin_k of d2 = (x2 - 2*cross) + p2, bit-exact vs
// numpy reference: cross = ((r*pr + g*pg) + b*pb), x2 = ((r*r+g*g)+b*b),
// d2 = (x2 - 2*cross) + p2, first-index tie-break (strict <).
//
// Exactness (verified R0/R2/R3/R5/R6/R7/R8/R9, absmax 0.0):
//  - contract(off): plain ops are the same IEEE RN ops as __f*_rn.
//  - pre-doubled pixels: fl(2r*pr)=2*fl(r*pr), fl(2x+2y)=2*fl(x+y) exact.
//  - k=0 seed == +inf seed with strict <.
//  - packed v2f per-element IEEE RN == scalar.
//  - p2 computed once per block (same tree per color => identical bits).
// BANNED: nontemporal stores (R1); readfirstlane SGPR arrays (R4);
// launch_bounds min-waves cap (R4/R6); PPT=2 (R7); paced pipeline @ half
// residency (R3); upfront 2-tile prefetch (R8 null).
//
// R9 diagnostics: VALU fully serial w/ memory; R5 split = VALU 14.4 us +
// mem 9.2 us; pk_f32 = 4.2 cyc (no packing gain). R10 trims VALU fat:
//  - p2[16] computed by lanes 0-15 into LDS, broadcast into regs (saves
//    ~128 instr/wave of SGPR-mov/mul fat).
//  - +p2 as two scalar adds on v2f halves (no dup movs).
//  - s_setprio(1) around the k-loop (independent waves; m191 attn +4-7%).

typedef float v2f __attribute__((ext_vector_type(2)));

constexpr int HW    = 512 * 512;   // 2^18
constexpr int KCOL  = 16;
constexpr long NPIX = 16L * HW;    // 4,194,304
constexpr int PPT   = 4;

__global__ __launch_bounds__(256) void color_reduce_kernel(
    const float* __restrict__ x,       // (B, 3, H, W)
    const float* __restrict__ pal,     // (16, 3)
    float* __restrict__ out)           // (B, 3, H, W)
{
#pragma clang fp contract(off)
    __shared__ float spal[KCOL * 3];
    __shared__ float sp2[KCOL];
    if (threadIdx.x < KCOL * 3) spal[threadIdx.x] = pal[threadIdx.x];
    if (threadIdx.x < KCOL) {
        const float pr = pal[3 * threadIdx.x + 0];
        const float pg = pal[3 * threadIdx.x + 1];
        const float pb = pal[3 * threadIdx.x + 2];
        sp2[threadIdx.x] = ((pr * pr) + (pg * pg)) + (pb * pb);  // exact tree
    }
    __syncthreads();

    const long t  = (long)blockIdx.x * blockDim.x + threadIdx.x;
    const long n0 = t * PPT;
    const int b   = (int)(n0 >> 18);        // n0 / HW
    const int pix = (int)(n0 & (HW - 1));   // n0 % HW

    const float* base = x + (size_t)b * 3 * HW + pix;
    const float4 rv = *reinterpret_cast<const float4*>(base);
    const float4 gv = *reinterpret_cast<const float4*>(base + HW);
    const float4 bv = *reinterpret_cast<const float4*>(base + 2 * HW);

    // p2 broadcast: 16 ds_read_b32 (uniform addr), statically indexed -> regs.
    float p2r[KCOL];
#pragma unroll
    for (int k = 0; k < KCOL; ++k) p2r[k] = sp2[k];

    const v2f rA = {rv.x, rv.y}, rB = {rv.z, rv.w};
    const v2f gA = {gv.x, gv.y}, gB = {gv.z, gv.w};
    const v2f bA = {bv.x, bv.y}, bB = {bv.z, bv.w};

    const v2f x2A = ((rA * rA) + (gA * gA)) + (bA * bA);
    const v2f x2B = ((rB * rB) + (gB * gB)) + (bB * bB);

    const v2f r2A = rA + rA, g2A = gA + gA, b2A = bA + bA;
    const v2f r2B = rB + rB, g2B = gB + gB, b2B = bB + bB;

    float best0, best1, best2, best3;
    int   k0 = 0, k1 = 0, k2 = 0, k3 = 0;

    __builtin_amdgcn_s_setprio(1);

    {   // k = 0 seeds best (== +inf seed with strict <)
        const float pr = pal[0], pg = pal[1], pb = pal[2];
        const v2f prv = {pr, pr}, pgv = {pg, pg}, pbv = {pb, pb};
        const v2f crA = ((r2A * prv) + (g2A * pgv)) + (b2A * pbv);  // == 2*cross
        const v2f crB = ((r2B * prv) + (g2B * pgv)) + (b2B * pbv);
        const v2f sA  = x2A - crA;
        const v2f sB  = x2B - crB;
        best0 = sA.x + p2r[0]; best1 = sA.y + p2r[0];               // exact d2
        best2 = sB.x + p2r[0]; best3 = sB.y + p2r[0];
    }

#pragma unroll
    for (int k = 1; k < KCOL; ++k) {
        const float pr = pal[3 * k + 0];   // uniform -> s_load/SGPR
        const float pg = pal[3 * k + 1];
        const float pb = pal[3 * k + 2];
        const v2f prv = {pr, pr}, pgv = {pg, pg}, pbv = {pb, pb};
        const v2f crA = ((r2A * prv) + (g2A * pgv)) + (b2A * pbv);
        const v2f crB = ((r2B * prv) + (g2B * pgv)) + (b2B * pbv);
        const v2f sA  = x2A - crA;
        const v2f sB  = x2B - crB;
        const float d0 = sA.x + p2r[k];
        const float d1 = sA.y + p2r[k];
        const float d2 = sB.x + p2r[k];
        const float d3 = sB.y + p2r[k];
        if (d0 < best0) { best0 = d0; k0 = k; }   // strict <: np.argmin
        if (d1 < best1) { best1 = d1; k1 = k; }
        if (d2 < best2) { best2 = d2; k2 = k; }
        if (d3 < best3) { best3 = d3; k3 = k; }
    }

    __builtin_amdgcn_s_setprio(0);

    // Gather winning colors from LDS palette.
    const float o0r = spal[3 * k0 + 0], o0g = spal[3 * k0 + 1], o0b = spal[3 * k0 + 2];
    const float o1r = spal[3 * k1 + 0], o1g = spal[3 * k1 + 1], o1b = spal[3 * k1 + 2];
    const float o2r = spal[3 * k2 + 0], o2g = spal[3 * k2 + 1], o2b = spal[3 * k2 + 2];
    const float o3r = spal[3 * k3 + 0], o3g = spal[3 * k3 + 1], o3b = spal[3 * k3 + 2];

    float* ob = out + (size_t)b * 3 * HW + pix;
    *reinterpret_cast<float4*>(ob)          = make_float4(o0r, o1r, o2r, o3r);
    *reinterpret_cast<float4*>(ob + HW)     = make_float4(o0g, o1g, o2g, o3g);
    *reinterpret_cast<float4*>(ob + 2 * HW) = make_float4(o0b, o1b, o2b, o3b);
}

extern "C" void kernel_launch(void* const* d_in, const int* in_sizes, int n_in,
                              void* d_out, int out_size, void* d_ws, size_t ws_size,
                              hipStream_t stream) {
    const float* x   = (const float*)d_in[0];
    const float* pal = (const float*)d_in[1];
    float* out       = (float*)d_out;

    const int threads = 256;
    const long total_threads = NPIX / PPT;              // 1,048,576
    const int blocks = (int)(total_threads / threads);  // 4096
    color_reduce_kernel<<<blocks, threads, 0, stream>>>(x, pal, out);
}

// Round 12
// 24.116 us; speedup vs baseline: 2.1637x; 1.0624x over previous
//
#include <hip/hip_runtime.h>

// ColorReducer: per-pixel argmin_k of d2 = (x2 - 2*cross) + p2, bit-exact vs
// numpy reference: cross = ((r*pr + g*pg) + b*pb), x2 = ((r*r+g*g)+b*b),
// d2 = (x2 - 2*cross) + p2, first-index tie-break (strict <).
//
// Exactness (verified R0/R2/R3/R5..R10, absmax 0.0): contract(off);
// pre-doubled pixels (fl(2r*pr)=2*fl(r*pr), fl(2x+2y)=2*fl(x+y) exact);
// k=0 seed == +inf seed with strict <; packed v2f per-element IEEE RN.
// BANNED: nt stores (R1); readfirstlane arrays (R4); launch_bounds cap
// (R4/R6); PPT=2 (R7); half-residency (R3); setprio/LDS-p2 (R10, -2us).
//
// R11 theory: traffic is BURSTY (load burst -> compute w/ idle memory ->
// store burst). R8 (all loads upfront) just made one bigger burst. This
// round: tile-2 loads issued MID-k-loop of tile-1, pinned by an asm memory
// fence (anti-hoist). Tile-1 stores drain under tile-2 compute.
// Math = R5 verbatim.

typedef float v2f __attribute__((ext_vector_type(2)));

constexpr int HW      = 512 * 512;   // 2^18
constexpr int KCOL    = 16;
constexpr int PPT     = 4;
constexpr int THREADS = 256;
constexpr int BLOCKS  = 2048;        // x2 tiles/thread = full coverage

struct Px4 {
    v2f x2A, x2B, r2A, g2A, b2A, r2B, g2B, b2B;
    float best0, best1, best2, best3;
    int   k0, k1, k2, k3;
};

__device__ __forceinline__ void init4(Px4& s, const float4 rv, const float4 gv,
                                      const float4 bv, const float* __restrict__ pal)
{
#pragma clang fp contract(off)
    const v2f rA = {rv.x, rv.y}, rB = {rv.z, rv.w};
    const v2f gA = {gv.x, gv.y}, gB = {gv.z, gv.w};
    const v2f bA = {bv.x, bv.y}, bB = {bv.z, bv.w};

    s.x2A = ((rA * rA) + (gA * gA)) + (bA * bA);   // exact reference tree
    s.x2B = ((rB * rB) + (gB * gB)) + (bB * bB);

    s.r2A = rA + rA; s.g2A = gA + gA; s.b2A = bA + bA;   // exact pre-double
    s.r2B = rB + rB; s.g2B = gB + gB; s.b2B = bB + bB;

    // k = 0 seeds best (== +inf seed with strict <)
    const float pr = pal[0], pg = pal[1], pb = pal[2];
    const float p2 = ((pr * pr) + (pg * pg)) + (pb * pb);
    const v2f prv = {pr, pr}, pgv = {pg, pg}, pbv = {pb, pb}, p2v = {p2, p2};
    const v2f crA = ((s.r2A * prv) + (s.g2A * pgv)) + (s.b2A * pbv);  // == 2*cross
    const v2f crB = ((s.r2B * prv) + (s.g2B * pgv)) + (s.b2B * pbv);
    const v2f dA  = (s.x2A - crA) + p2v;
    const v2f dB  = (s.x2B - crB) + p2v;
    s.best0 = dA.x; s.best1 = dA.y; s.best2 = dB.x; s.best3 = dB.y;
    s.k0 = 0; s.k1 = 0; s.k2 = 0; s.k3 = 0;
}

template <int KB, int KE>
__device__ __forceinline__ void scan(Px4& s, const float* __restrict__ pal)
{
#pragma clang fp contract(off)
#pragma unroll
    for (int k = KB; k < KE; ++k) {
        const float pr = pal[3 * k + 0];   // uniform -> s_load/SGPR
        const float pg = pal[3 * k + 1];
        const float pb = pal[3 * k + 2];
        const float p2 = ((pr * pr) + (pg * pg)) + (pb * pb);
        const v2f prv = {pr, pr}, pgv = {pg, pg}, pbv = {pb, pb}, p2v = {p2, p2};
        const v2f crA = ((s.r2A * prv) + (s.g2A * pgv)) + (s.b2A * pbv);
        const v2f crB = ((s.r2B * prv) + (s.g2B * pgv)) + (s.b2B * pbv);
        const v2f dA  = (s.x2A - crA) + p2v;
        const v2f dB  = (s.x2B - crB) + p2v;
        if (dA.x < s.best0) { s.best0 = dA.x; s.k0 = k; }   // strict <
        if (dA.y < s.best1) { s.best1 = dA.y; s.k1 = k; }
        if (dB.x < s.best2) { s.best2 = dB.x; s.k2 = k; }
        if (dB.y < s.best3) { s.best3 = dB.y; s.k3 = k; }
    }
}

__device__ __forceinline__ void gather_store(const Px4& s, const float* spal,
                                             float* __restrict__ ob)
{
    const float o0r = spal[3 * s.k0 + 0], o0g = spal[3 * s.k0 + 1], o0b = spal[3 * s.k0 + 2];
    const float o1r = spal[3 * s.k1 + 0], o1g = spal[3 * s.k1 + 1], o1b = spal[3 * s.k1 + 2];
    const float o2r = spal[3 * s.k2 + 0], o2g = spal[3 * s.k2 + 1], o2b = spal[3 * s.k2 + 2];
    const float o3r = spal[3 * s.k3 + 0], o3g = spal[3 * s.k3 + 1], o3b = spal[3 * s.k3 + 2];

    *reinterpret_cast<float4*>(ob)          = make_float4(o0r, o1r, o2r, o3r);
    *reinterpret_cast<float4*>(ob + HW)     = make_float4(o0g, o1g, o2g, o3g);
    *reinterpret_cast<float4*>(ob + 2 * HW) = make_float4(o0b, o1b, o2b, o3b);
}

__global__ __launch_bounds__(THREADS) void color_reduce_kernel(
    const float* __restrict__ x,       // (B, 3, H, W)
    const float* __restrict__ pal,     // (16, 3)
    float* __restrict__ out)           // (B, 3, H, W)
{
    __shared__ float spal[KCOL * 3];
    if (threadIdx.x < KCOL * 3) spal[threadIdx.x] = pal[threadIdx.x];
    __syncthreads();

    const int t4  = (blockIdx.x * THREADS + threadIdx.x) * PPT;  // < 2^21
    const int b0  = t4 >> 18;              // in [0, 8)
    const int pix = t4 & (HW - 1);

    const float* base0 = x + (size_t)b0 * 3 * HW + pix;
    const float* base1 = base0 + (size_t)8 * 3 * HW;   // tile 2: b0+8, same pix
    float* ob0 = out + (size_t)b0 * 3 * HW + pix;
    float* ob1 = ob0 + (size_t)8 * 3 * HW;

    // ---- tile 1 loads ----
    const float4 rv0 = *reinterpret_cast<const float4*>(base0);
    const float4 gv0 = *reinterpret_cast<const float4*>(base0 + HW);
    const float4 bv0 = *reinterpret_cast<const float4*>(base0 + 2 * HW);

    Px4 s1;
    init4(s1, rv0, gv0, bv0, pal);
    scan<1, 8>(s1, pal);                   // first half of tile-1 compute

    // ---- anti-hoist fence: tile-2 loads issue HERE, mid-compute ----
    asm volatile("" ::: "memory");
    const float4 rv1 = *reinterpret_cast<const float4*>(base1);
    const float4 gv1 = *reinterpret_cast<const float4*>(base1 + HW);
    const float4 bv1 = *reinterpret_cast<const float4*>(base1 + 2 * HW);

    scan<8, 16>(s1, pal);                  // second half of tile-1 compute
    gather_store(s1, spal, ob0);           // stores drain under tile-2 compute

    Px4 s2;
    init4(s2, rv1, gv1, bv1, pal);
    scan<1, 16>(s2, pal);
    gather_store(s2, spal, ob1);
}

extern "C" void kernel_launch(void* const* d_in, const int* in_sizes, int n_in,
                              void* d_out, int out_size, void* d_ws, size_t ws_size,
                              hipStream_t stream) {
    const float* x   = (const float*)d_in[0];
    const float* pal = (const float*)d_in[1];
    float* out       = (float*)d_out;

    color_reduce_kernel<<<BLOCKS, THREADS, 0, stream>>>(x, pal, out);
}

// Round 13
// 23.994 us; speedup vs baseline: 2.1748x; 1.0051x over previous
//
#include <hip/hip_runtime.h>

// ColorReducer: per-pixel argmin_k of d2 = (x2 - 2*cross) + p2, bit-exact vs
// numpy reference: cross = ((r*pr + g*pg) + b*pb), x2 = ((r*r+g*g)+b*b),
// d2 = (x2 - 2*cross) + p2, first-index tie-break (strict <).
//
// Exactness (verified R0/R2/R3/R5/R6/R7/R8/R9/R11, absmax 0.0):
//  - contract(off): plain ops are the same IEEE RN ops as __f*_rn.
//  - pre-doubled pixels: fl(2r*pr)=2*fl(r*pr), fl(2x+2y)=2*fl(x+y) exact
//    -> ((2r*pr+2g*pg)+2b*pb) == 2*cross bitwise; in-place doubling after
//    x2 proven by R6 (its regression was the bundled launch-bounds cap).
//  - k=0 seed == +inf seed with strict <.
//  - packed v2f per-element IEEE RN == scalar.
// BANNED: nt stores (R1); readfirstlane arrays (R4); launch_bounds cap
// (R4/R6); PPT=2 (R7); half-residency (R3); setprio/LDS-p2 (R10);
// mid-loop fenced loads (R11 null).
//
// R9 decomposition: VALU 14.4 us (fully exposed) + mem 9.2 us. VALU floor
// ~10 us; the gap is per-thread fat (per-k palette prep ~8 ops amortized
// over only 4 px; addresses; gather setup) paid over 2 generations.
// R12: PPT=8 in ONE fused k-loop (per-k palette fat halves per px; one
// resident generation of 2048 blocks; R8's version recomputed palette
// constants per tile and shared nothing). Math = R5 verbatim.

typedef float v2f __attribute__((ext_vector_type(2)));

constexpr int HW      = 512 * 512;   // 2^18
constexpr int KCOL    = 16;
constexpr long NPIX   = 16L * HW;    // 4,194,304
constexpr int PPT     = 8;
constexpr int THREADS = 256;
constexpr int BLOCKS  = (int)(NPIX / ((long)PPT * THREADS));   // 2048

__global__ __launch_bounds__(THREADS) void color_reduce_kernel(
    const float* __restrict__ x,       // (B, 3, H, W)
    const float* __restrict__ pal,     // (16, 3)
    float* __restrict__ out)           // (B, 3, H, W)
{
#pragma clang fp contract(off)
    __shared__ float spal[KCOL * 3];
    if (threadIdx.x < KCOL * 3) spal[threadIdx.x] = pal[threadIdx.x];
    __syncthreads();

    const int t8  = (blockIdx.x * THREADS + threadIdx.x) * PPT;  // < 2^22
    const int b   = t8 >> 18;              // t8 / HW
    const int pix = t8 & (HW - 1);         // t8 % HW

    const float* base = x + (size_t)b * 3 * HW + pix;
    const float4 r0 = *reinterpret_cast<const float4*>(base);
    const float4 r1 = *reinterpret_cast<const float4*>(base + 4);
    const float4 g0 = *reinterpret_cast<const float4*>(base + HW);
    const float4 g1 = *reinterpret_cast<const float4*>(base + HW + 4);
    const float4 b0 = *reinterpret_cast<const float4*>(base + 2 * HW);
    const float4 b1 = *reinterpret_cast<const float4*>(base + 2 * HW + 4);

    // 8 px as 4 packed pairs; x2 from originals, then double IN PLACE.
    v2f r2[4] = {{r0.x, r0.y}, {r0.z, r0.w}, {r1.x, r1.y}, {r1.z, r1.w}};
    v2f g2[4] = {{g0.x, g0.y}, {g0.z, g0.w}, {g1.x, g1.y}, {g1.z, g1.w}};
    v2f b2[4] = {{b0.x, b0.y}, {b0.z, b0.w}, {b1.x, b1.y}, {b1.z, b1.w}};
    v2f x2[4];
#pragma unroll
    for (int i = 0; i < 4; ++i) {
        x2[i] = ((r2[i] * r2[i]) + (g2[i] * g2[i])) + (b2[i] * b2[i]); // exact tree
        r2[i] = r2[i] + r2[i];   // exact doubling; originals dead after x2
        g2[i] = g2[i] + g2[i];
        b2[i] = b2[i] + b2[i];
    }

    float best[8];
    int   bk[8];

    {   // k = 0 seeds best (== +inf seed with strict <)
        const float pr = pal[0], pg = pal[1], pb = pal[2];
        const float p2 = ((pr * pr) + (pg * pg)) + (pb * pb);
        const v2f prv = {pr, pr}, pgv = {pg, pg}, pbv = {pb, pb}, p2v = {p2, p2};
#pragma unroll
        for (int i = 0; i < 4; ++i) {
            const v2f cr = ((r2[i] * prv) + (g2[i] * pgv)) + (b2[i] * pbv); // ==2*cross
            const v2f d  = (x2[i] - cr) + p2v;                              // exact d2
            best[2 * i]     = d.x;  bk[2 * i]     = 0;
            best[2 * i + 1] = d.y;  bk[2 * i + 1] = 0;
        }
    }

#pragma unroll
    for (int k = 1; k < KCOL; ++k) {
        const float pr = pal[3 * k + 0];   // uniform -> s_load/SGPR
        const float pg = pal[3 * k + 1];
        const float pb = pal[3 * k + 2];
        const float p2 = ((pr * pr) + (pg * pg)) + (pb * pb);
        const v2f prv = {pr, pr}, pgv = {pg, pg}, pbv = {pb, pb}, p2v = {p2, p2};
#pragma unroll
        for (int i = 0; i < 4; ++i) {
            const v2f cr = ((r2[i] * prv) + (g2[i] * pgv)) + (b2[i] * pbv);
            const v2f d  = (x2[i] - cr) + p2v;
            if (d.x < best[2 * i])     { best[2 * i]     = d.x; bk[2 * i]     = k; }
            if (d.y < best[2 * i + 1]) { best[2 * i + 1] = d.y; bk[2 * i + 1] = k; }
        }
    }

    // Gather winning colors from LDS palette (static indexing).
    float orr[8], ogg[8], obb[8];
#pragma unroll
    for (int i = 0; i < 8; ++i) {
        orr[i] = spal[3 * bk[i] + 0];
        ogg[i] = spal[3 * bk[i] + 1];
        obb[i] = spal[3 * bk[i] + 2];
    }

    float* ob = out + (size_t)b * 3 * HW + pix;
    *reinterpret_cast<float4*>(ob)              = make_float4(orr[0], orr[1], orr[2], orr[3]);
    *reinterpret_cast<float4*>(ob + 4)          = make_float4(orr[4], orr[5], orr[6], orr[7]);
    *reinterpret_cast<float4*>(ob + HW)         = make_float4(ogg[0], ogg[1], ogg[2], ogg[3]);
    *reinterpret_cast<float4*>(ob + HW + 4)     = make_float4(ogg[4], ogg[5], ogg[6], ogg[7]);
    *reinterpret_cast<float4*>(ob + 2 * HW)     = make_float4(obb[0], obb[1], obb[2], obb[3]);
    *reinterpret_cast<float4*>(ob + 2 * HW + 4) = make_float4(obb[4], obb[5], obb[6], obb[7]);
}

extern "C" void kernel_launch(void* const* d_in, const int* in_sizes, int n_in,
                              void* d_out, int out_size, void* d_ws, size_t ws_size,
                              hipStream_t stream) {
    const float* x   = (const float*)d_in[0];
    const float* pal = (const float*)d_in[1];
    float* out       = (float*)d_out;

    color_reduce_kernel<<<BLOCKS, THREADS, 0, stream>>>(x, pal, out);
}